// Round 2
// baseline (987.717 us; speedup 1.0000x reference)
//
#include <hip/hip_runtime.h>
#include <cstdint>
#include <cstddef>

#define B_    32
#define P_    16384
#define C_    80
#define NOBJ_ 50
#define THRESH_ 0.5f

static constexpr size_t OFF_ACC   = 0;
static constexpr size_t OFF_NNEG  = 512;
static constexpr size_t OFF_BP    = 1024;
static constexpr size_t OFF_BTOVL = 8192;
static constexpr size_t SZ_BP32   = (size_t)B_ * P_ * 4;
static constexpr size_t OFF_BTIDX = OFF_BTOVL + SZ_BP32;
static constexpr size_t OFF_MINEC = OFF_BTIDX + SZ_BP32;
static constexpr size_t OFF_MINEO = OFF_MINEC + SZ_BP32;
static constexpr size_t OFF_W     = OFF_MINEO + SZ_BP32;
static constexpr size_t OFF_POS   = OFF_W + SZ_BP32;

__device__ __forceinline__ unsigned fkey(float f) {
    unsigned u = __float_as_uint(f);
    return (u & 0x80000000u) ? ~u : (u | 0x80000000u);
}

// Wave-aggregated histogram add: lanes with equal `bin` are merged into one
// atomic of the lane count. Hot-bin case (all 64 lanes same bin) = 1 atomic.
__device__ __forceinline__ void wave_hist_add(unsigned bin, unsigned* hist) {
    int lane = threadIdx.x & 63;
    unsigned long long active = __ballot(1);
    while (true) {
        int leader = __ffsll((long long)active) - 1;
        unsigned lbin = __shfl(bin, leader);
        unsigned long long same = __ballot(bin == lbin);
        if (bin == lbin) {
            if (lane == leader) atomicAdd(&hist[lbin], (unsigned)__popcll(same));
            break;
        }
        active &= ~same;
    }
}

__device__ double block_reduce_d(double v, double* sh, int nthreads) {
    int tid = threadIdx.x;
    sh[tid] = v; __syncthreads();
    for (int s = nthreads >> 1; s > 0; s >>= 1) {
        if (tid < s) sh[tid] += sh[tid + s];
        __syncthreads();
    }
    double r = sh[0]; __syncthreads();
    return r;
}

// Per-prior best truth (argmax over axis=0, first-index tie-break)
__global__ __launch_bounds__(256) void k_match_prior(
    const float* __restrict__ priors, const float* __restrict__ targets,
    float* __restrict__ btovl, int* __restrict__ btidx)
{
    int b = blockIdx.y;
    int p = blockIdx.x * 256 + threadIdx.x;
    __shared__ float tg[NOBJ_ * 6];
    __shared__ float areaA[NOBJ_];
    for (int i = threadIdx.x; i < NOBJ_ * 6; i += 256) tg[i] = targets[(size_t)b * NOBJ_ * 6 + i];
    __syncthreads();
    if (threadIdx.x < NOBJ_) {
        int t = threadIdx.x;
        areaA[t] = (tg[t*6+2] - tg[t*6+0]) * (tg[t*6+3] - tg[t*6+1]);
    }
    __syncthreads();
    float cx = priors[p*4], cy = priors[p*4+1], pw = priors[p*4+2], ph = priors[p*4+3];
    float bx1 = cx - pw*0.5f, by1 = cy - ph*0.5f, bx2 = cx + pw*0.5f, by2 = cy + ph*0.5f;
    float areaB = (bx2 - bx1) * (by2 - by1);
    float best = -1.0f; int bi = 0;
    for (int t = 0; t < NOBJ_; ++t) {
        float lx = fmaxf(tg[t*6+0], bx1), ly = fmaxf(tg[t*6+1], by1);
        float rx = fminf(tg[t*6+2], bx2), ry = fminf(tg[t*6+3], by2);
        float iw = fmaxf(rx - lx, 0.f), ih = fmaxf(ry - ly, 0.f);
        float inter = iw * ih;
        float iou = inter / (areaA[t] + areaB - inter);
        if (iou > best) { best = iou; bi = t; }
    }
    size_t ip = (size_t)b * P_ + p;
    btovl[ip] = best; btidx[ip] = bi;
}

// Per-truth best prior (argmax over axis=1, first-index tie-break)
__global__ __launch_bounds__(256) void k_best_prior(
    const float* __restrict__ priors, const float* __restrict__ targets,
    int* __restrict__ bp)
{
    int t = blockIdx.x, b = blockIdx.y, tid = threadIdx.x;
    const float* tr = targets + (size_t)(b * NOBJ_ + t) * 6;
    float x1 = tr[0], y1 = tr[1], x2 = tr[2], y2 = tr[3];
    float areaA = (x2 - x1) * (y2 - y1);
    float best = -1.f; int bi = 0;
    for (int p = tid; p < P_; p += 256) {
        float cx = priors[p*4], cy = priors[p*4+1], pw = priors[p*4+2], ph = priors[p*4+3];
        float bx1 = cx - pw*0.5f, by1 = cy - ph*0.5f, bx2 = cx + pw*0.5f, by2 = cy + ph*0.5f;
        float areaB = (bx2 - bx1) * (by2 - by1);
        float lx = fmaxf(x1, bx1), ly = fmaxf(y1, by1);
        float rx = fminf(x2, bx2), ry = fminf(y2, by2);
        float iw = fmaxf(rx - lx, 0.f), ih = fmaxf(ry - ly, 0.f);
        float inter = iw * ih;
        float iou = inter / (areaA + areaB - inter);
        if (iou > best) { best = iou; bi = p; }
    }
    __shared__ float sv[256];
    __shared__ int   si[256];
    sv[tid] = best; si[tid] = bi; __syncthreads();
    for (int s = 128; s > 0; s >>= 1) {
        if (tid < s) {
            if (sv[tid+s] > sv[tid] || (sv[tid+s] == sv[tid] && si[tid+s] < si[tid])) {
                sv[tid] = sv[tid+s]; si[tid] = si[tid+s];
            }
        }
        __syncthreads();
    }
    if (tid == 0) bp[b * NOBJ_ + t] = si[0];
}

// Sequential last-wins scatter per batch (numpy/XLA in-order semantics)
__global__ void k_scatter(const int* __restrict__ bp,
                          float* __restrict__ btovl, int* __restrict__ btidx)
{
    int b = threadIdx.x;
    if (b >= B_) return;
    for (int i = 0; i < NOBJ_; ++i) {
        int p = bp[b * NOBJ_ + i];
        btovl[(size_t)b * P_ + p] = 2.0f;
        btidx[(size_t)b * P_ + p] = i;
    }
}

__global__ __launch_bounds__(256) void k_main(
    const float* __restrict__ loc, const float* __restrict__ conf,
    const float* __restrict__ obj, const float* __restrict__ priors,
    const float* __restrict__ targets,
    const float* __restrict__ btovl, const int* __restrict__ btidx,
    float* __restrict__ mine_c, float* __restrict__ mine_o,
    float* __restrict__ wArr, uint8_t* __restrict__ posArr,
    double* __restrict__ acc)
{
    int b = blockIdx.y;
    int p = blockIdx.x * 256 + threadIdx.x;
    __shared__ float tg[NOBJ_ * 6];
    __shared__ double rd[256];
    for (int i = threadIdx.x; i < NOBJ_ * 6; i += 256) tg[i] = targets[(size_t)b * NOBJ_ * 6 + i];
    __syncthreads();
    size_t ip = (size_t)b * P_ + p;
    float ov = btovl[ip];
    int   ti = btidx[ip];
    float w  = tg[ti*6+5];
    bool pos = ov >= THRESH_;
    int  tgt = pos ? (int)tg[ti*6+4] : 0;

    float tx1 = tg[ti*6+0], ty1 = tg[ti*6+1], tx2 = tg[ti*6+2], ty2 = tg[ti*6+3];
    float cx = priors[p*4], cy = priors[p*4+1], pw = priors[p*4+2], ph = priors[p*4+3];
    float gx = ((tx1 + tx2) * 0.5f - cx) / (0.1f * pw);
    float gy = ((ty1 + ty2) * 0.5f - cy) / (0.1f * ph);
    float gw = logf((tx2 - tx1) / pw) * 5.0f;
    float gh = logf((ty2 - ty1) / ph) * 5.0f;

    const float* lr = loc + ip * 4;
    float sl1 = 0.f;
    {
        float g[4] = {gx, gy, gw, gh};
        #pragma unroll
        for (int k = 0; k < 4; ++k) {
            float d = lr[k] - g[k];
            float ad = fabsf(d);
            sl1 += (ad < 1.0f) ? 0.5f * d * d : ad - 0.5f;
        }
    }

    float o0 = obj[ip*2], o1 = obj[ip*2+1];
    float mo = fmaxf(o0, o1);
    float lae = mo + logf(expf(o0 - mo) + expf(o1 - mo));

    const float4* cr = (const float4*)(conf + ip * C_);
    float m = -INFINITY, s = 0.f;
    #pragma unroll 4
    for (int k = 0; k < C_ / 4; ++k) {
        float4 v = cr[k];
        float m4 = fmaxf(fmaxf(v.x, v.y), fmaxf(v.z, v.w));
        float nm = fmaxf(m, m4);
        s = s * expf(m - nm) + expf(v.x - nm) + expf(v.y - nm) + expf(v.z - nm) + expf(v.w - nm);
        m = nm;
    }
    float lse = m + logf(s);

    float ce_o = lae - (pos ? o1 : o0);
    float ce_c;
    if (tgt == 0) {
        ce_c = lae - o0;
    } else {
        float ctgt = conf[ip * C_ + (tgt - 1)];
        ce_c = lse + lae - o1 - ctgt;
    }

    mine_c[ip] = pos ? 0.f : ce_c;
    mine_o[ip] = pos ? 0.f : ce_o;
    wArr[ip]   = w;
    posArr[ip] = pos ? 1 : 0;

    double pl = pos ? (double)(sl1 * w)  : 0.0;
    double pc = pos ? (double)(ce_c * w) : 0.0;
    double po = pos ? (double)(ce_o * w) : 0.0;
    double pn = pos ? (double)w          : 0.0;

    double r;
    r = block_reduce_d(pl, rd, 256); if (threadIdx.x == 0) atomicAdd(&acc[0], r);
    r = block_reduce_d(pc, rd, 256); if (threadIdx.x == 0) atomicAdd(&acc[1], r);
    r = block_reduce_d(po, rd, 256); if (threadIdx.x == 0) atomicAdd(&acc[2], r);
    r = block_reduce_d(pn, rd, 256); if (threadIdx.x == 0) atomicAdd(&acc[3 + b], r);
}

__global__ void k_numneg(const double* __restrict__ acc, int* __restrict__ num_neg)
{
    int b = threadIdx.x;
    if (b >= B_) return;
    int np = (int)acc[3 + b];
    int nn = 3 * np;
    num_neg[b] = nn < (P_ - 1) ? nn : (P_ - 1);
}

#define SEL_T 1024
// Exact top-K selection per (batch, branch) via 3-pass radix histogram,
// with wave-aggregated shared atomics (hot-bin contention fix).
__global__ __launch_bounds__(SEL_T) void k_select(
    const float* __restrict__ mine_c, const float* __restrict__ mine_o,
    const float* __restrict__ wArr, const uint8_t* __restrict__ posArr,
    const int* __restrict__ num_neg, double* __restrict__ acc)
{
    int b = blockIdx.x;
    int branch = blockIdx.y; // 0 = conf, 1 = obj
    int tid = threadIdx.x;
    int K = num_neg[b];
    if (K <= 0) return;

    const float* mrow = (branch ? mine_o : mine_c) + (size_t)b * P_;
    const float* wrow = wArr + (size_t)b * P_;
    const uint8_t* prow = posArr + (size_t)b * P_;

    __shared__ unsigned hist[2048];
    __shared__ int s_bin, s_pre;
    __shared__ double rd[SEL_T];

    // pass 1: bits [31:21]
    for (int i = tid; i < 2048; i += SEL_T) hist[i] = 0;
    __syncthreads();
    for (int p = tid; p < P_; p += SEL_T) wave_hist_add(fkey(mrow[p]) >> 21, hist);
    __syncthreads();
    if (tid == 0) {
        unsigned a = 0; int bin = 2047;
        for (; bin >= 0; --bin) { unsigned h = hist[bin]; if (a + h >= (unsigned)K) break; a += h; }
        s_bin = bin; s_pre = (int)a;
    }
    __syncthreads();
    int bin1 = s_bin, pre1 = s_pre;

    // pass 2: bits [20:10] among elements with top bits == bin1
    __syncthreads();
    for (int i = tid; i < 2048; i += SEL_T) hist[i] = 0;
    __syncthreads();
    for (int p = tid; p < P_; p += SEL_T) {
        unsigned k = fkey(mrow[p]);
        if ((int)(k >> 21) == bin1) wave_hist_add((k >> 10) & 0x7FFu, hist);
    }
    __syncthreads();
    if (tid == 0) {
        int K2 = K - pre1;
        unsigned a = 0; int bin = 2047;
        for (; bin >= 0; --bin) { unsigned h = hist[bin]; if (a + h >= (unsigned)K2) break; a += h; }
        s_bin = bin; s_pre = (int)a;
    }
    __syncthreads();
    int bin2 = s_bin, pre2 = s_pre;

    // pass 3: bits [9:0]
    __syncthreads();
    for (int i = tid; i < 1024; i += SEL_T) hist[i] = 0;
    __syncthreads();
    unsigned hi21 = ((unsigned)bin1 << 11) | (unsigned)bin2;
    for (int p = tid; p < P_; p += SEL_T) {
        unsigned k = fkey(mrow[p]);
        if ((k >> 10) == hi21) wave_hist_add(k & 0x3FFu, hist);
    }
    __syncthreads();
    if (tid == 0) {
        int K3 = K - pre1 - pre2;
        unsigned a = 0; int bin = 1023;
        for (; bin >= 0; --bin) { unsigned h = hist[bin]; if (a + h >= (unsigned)K3) break; a += h; }
        s_bin = bin; s_pre = (int)a;
    }
    __syncthreads();
    int bin3 = s_bin, pre3 = s_pre;

    unsigned T = (hi21 << 10) | (unsigned)bin3;
    int mslots = K - (pre1 + pre2 + pre3);  // #selected among key==T, smallest index first

    double sum = 0.0;
    for (int p = tid; p < P_; p += SEL_T) {
        float v = mrow[p];
        unsigned k = fkey(v);
        if (k > T) {
            if (!prow[p]) sum += (double)v * (double)wrow[p];
        } else if (k == T && !prow[p] && v != 0.0f) {
            int e = 0;
            for (int q = 0; q < p; ++q) if (fkey(mrow[q]) == T) ++e;
            if (e < mslots) sum += (double)v * (double)wrow[p];
        }
    }
    double r = block_reduce_d(sum, rd, SEL_T);
    if (tid == 0) atomicAdd(&acc[1 + branch], r);
}

__global__ void k_final(const double* __restrict__ acc, float* __restrict__ out)
{
    if (threadIdx.x == 0) {
        double N = 0.0;
        for (int b = 0; b < B_; ++b) N += acc[3 + b];
        out[0] = (float)(acc[0] / N);
        out[1] = (float)(acc[1] / N);
        out[2] = (float)(acc[2] / N);
    }
}

extern "C" void kernel_launch(void* const* d_in, const int* in_sizes, int n_in,
                              void* d_out, int out_size, void* d_ws, size_t ws_size,
                              hipStream_t stream)
{
    const float* loc     = (const float*)d_in[0];
    const float* conf    = (const float*)d_in[1];
    const float* obj     = (const float*)d_in[2];
    const float* priors  = (const float*)d_in[3];
    const float* targets = (const float*)d_in[4];
    float* out = (float*)d_out;

    char* ws = (char*)d_ws;
    double*  acc    = (double*)(ws + OFF_ACC);
    int*     nneg   = (int*)(ws + OFF_NNEG);
    int*     bp     = (int*)(ws + OFF_BP);
    float*   btovl  = (float*)(ws + OFF_BTOVL);
    int*     btidx  = (int*)(ws + OFF_BTIDX);
    float*   mine_c = (float*)(ws + OFF_MINEC);
    float*   mine_o = (float*)(ws + OFF_MINEO);
    float*   wArr   = (float*)(ws + OFF_W);
    uint8_t* posArr = (uint8_t*)(ws + OFF_POS);

    hipMemsetAsync(ws, 0, 512, stream);

    k_match_prior<<<dim3(P_/256, B_), 256, 0, stream>>>(priors, targets, btovl, btidx);
    k_best_prior <<<dim3(NOBJ_, B_), 256, 0, stream>>>(priors, targets, bp);
    k_scatter    <<<1, 64, 0, stream>>>(bp, btovl, btidx);
    k_main       <<<dim3(P_/256, B_), 256, 0, stream>>>(loc, conf, obj, priors, targets,
                                                        btovl, btidx, mine_c, mine_o,
                                                        wArr, posArr, acc);
    k_numneg     <<<1, 64, 0, stream>>>(acc, nneg);
    k_select     <<<dim3(B_, 2), SEL_T, 0, stream>>>(mine_c, mine_o, wArr, posArr, nneg, acc);
    k_final      <<<1, 64, 0, stream>>>(acc, out);
}

// Round 3
// 260.451 us; speedup vs baseline: 3.7923x; 3.7923x over previous
//
#include <hip/hip_runtime.h>
#include <cstdint>
#include <cstddef>

#define B_    32
#define P_    16384
#define C_    80
#define NOBJ_ 50
#define THRESH_ 0.5f

static constexpr size_t OFF_ACC   = 0;
static constexpr size_t OFF_NNEG  = 512;
static constexpr size_t OFF_BP    = 1024;
static constexpr size_t OFF_BTOVL = 8192;
static constexpr size_t SZ_BP32   = (size_t)B_ * P_ * 4;
static constexpr size_t OFF_BTIDX = OFF_BTOVL + SZ_BP32;
static constexpr size_t OFF_MINEC = OFF_BTIDX + SZ_BP32;
static constexpr size_t OFF_MINEO = OFF_MINEC + SZ_BP32;
static constexpr size_t OFF_W     = OFF_MINEO + SZ_BP32;
static constexpr size_t OFF_POS   = OFF_W + SZ_BP32;

__device__ __forceinline__ unsigned fkey(float f) {
    unsigned u = __float_as_uint(f);
    return (u & 0x80000000u) ? ~u : (u | 0x80000000u);
}

// Wave-aggregated histogram add: lanes with equal `bin` merge into one atomic.
__device__ __forceinline__ void wave_hist_add(unsigned bin, unsigned* hist) {
    int lane = threadIdx.x & 63;
    unsigned long long active = __ballot(1);
    while (true) {
        int leader = __ffsll((long long)active) - 1;
        unsigned lbin = __shfl(bin, leader);
        unsigned long long same = __ballot(bin == lbin);
        if (bin == lbin) {
            if (lane == leader) atomicAdd(&hist[lbin], (unsigned)__popcll(same));
            break;
        }
        active &= ~same;
    }
}

__device__ double block_reduce_d(double v, double* sh, int nthreads) {
    int tid = threadIdx.x;
    sh[tid] = v; __syncthreads();
    for (int s = nthreads >> 1; s > 0; s >>= 1) {
        if (tid < s) sh[tid] += sh[tid + s];
        __syncthreads();
    }
    double r = sh[0]; __syncthreads();
    return r;
}

// Per-prior best truth (argmax over axis=0, first-index tie-break)
__global__ __launch_bounds__(256) void k_match_prior(
    const float* __restrict__ priors, const float* __restrict__ targets,
    float* __restrict__ btovl, int* __restrict__ btidx)
{
    int b = blockIdx.y;
    int p = blockIdx.x * 256 + threadIdx.x;
    __shared__ float tg[NOBJ_ * 6];
    __shared__ float areaA[NOBJ_];
    for (int i = threadIdx.x; i < NOBJ_ * 6; i += 256) tg[i] = targets[(size_t)b * NOBJ_ * 6 + i];
    __syncthreads();
    if (threadIdx.x < NOBJ_) {
        int t = threadIdx.x;
        areaA[t] = (tg[t*6+2] - tg[t*6+0]) * (tg[t*6+3] - tg[t*6+1]);
    }
    __syncthreads();
    float cx = priors[p*4], cy = priors[p*4+1], pw = priors[p*4+2], ph = priors[p*4+3];
    float bx1 = cx - pw*0.5f, by1 = cy - ph*0.5f, bx2 = cx + pw*0.5f, by2 = cy + ph*0.5f;
    float areaB = (bx2 - bx1) * (by2 - by1);
    float best = -1.0f; int bi = 0;
    for (int t = 0; t < NOBJ_; ++t) {
        float lx = fmaxf(tg[t*6+0], bx1), ly = fmaxf(tg[t*6+1], by1);
        float rx = fminf(tg[t*6+2], bx2), ry = fminf(tg[t*6+3], by2);
        float iw = fmaxf(rx - lx, 0.f), ih = fmaxf(ry - ly, 0.f);
        float inter = iw * ih;
        float iou = inter / (areaA[t] + areaB - inter);
        if (iou > best) { best = iou; bi = t; }
    }
    size_t ip = (size_t)b * P_ + p;
    btovl[ip] = best; btidx[ip] = bi;
}

// Per-truth best prior (argmax over axis=1, first-index tie-break)
__global__ __launch_bounds__(256) void k_best_prior(
    const float* __restrict__ priors, const float* __restrict__ targets,
    int* __restrict__ bp)
{
    int t = blockIdx.x, b = blockIdx.y, tid = threadIdx.x;
    const float* tr = targets + (size_t)(b * NOBJ_ + t) * 6;
    float x1 = tr[0], y1 = tr[1], x2 = tr[2], y2 = tr[3];
    float areaA = (x2 - x1) * (y2 - y1);
    float best = -1.f; int bi = 0;
    for (int p = tid; p < P_; p += 256) {
        float cx = priors[p*4], cy = priors[p*4+1], pw = priors[p*4+2], ph = priors[p*4+3];
        float bx1 = cx - pw*0.5f, by1 = cy - ph*0.5f, bx2 = cx + pw*0.5f, by2 = cy + ph*0.5f;
        float areaB = (bx2 - bx1) * (by2 - by1);
        float lx = fmaxf(x1, bx1), ly = fmaxf(y1, by1);
        float rx = fminf(x2, bx2), ry = fminf(y2, by2);
        float iw = fmaxf(rx - lx, 0.f), ih = fmaxf(ry - ly, 0.f);
        float inter = iw * ih;
        float iou = inter / (areaA + areaB - inter);
        if (iou > best) { best = iou; bi = p; }
    }
    __shared__ float sv[256];
    __shared__ int   si[256];
    sv[tid] = best; si[tid] = bi; __syncthreads();
    for (int s = 128; s > 0; s >>= 1) {
        if (tid < s) {
            if (sv[tid+s] > sv[tid] || (sv[tid+s] == sv[tid] && si[tid+s] < si[tid])) {
                sv[tid] = sv[tid+s]; si[tid] = si[tid+s];
            }
        }
        __syncthreads();
    }
    if (tid == 0) bp[b * NOBJ_ + t] = si[0];
}

// Sequential last-wins scatter per batch (numpy/XLA in-order semantics)
__global__ void k_scatter(const int* __restrict__ bp,
                          float* __restrict__ btovl, int* __restrict__ btidx)
{
    int b = threadIdx.x;
    if (b >= B_) return;
    for (int i = 0; i < NOBJ_; ++i) {
        int p = bp[b * NOBJ_ + i];
        btovl[(size_t)b * P_ + p] = 2.0f;
        btidx[(size_t)b * P_ + p] = i;
    }
}

__global__ __launch_bounds__(256) void k_main(
    const float* __restrict__ loc, const float* __restrict__ conf,
    const float* __restrict__ obj, const float* __restrict__ priors,
    const float* __restrict__ targets,
    const float* __restrict__ btovl, const int* __restrict__ btidx,
    float* __restrict__ mine_c, float* __restrict__ mine_o,
    float* __restrict__ wArr, uint8_t* __restrict__ posArr,
    double* __restrict__ acc)
{
    int b = blockIdx.y;
    int p = blockIdx.x * 256 + threadIdx.x;
    __shared__ float tg[NOBJ_ * 6];
    __shared__ double rd[256];
    for (int i = threadIdx.x; i < NOBJ_ * 6; i += 256) tg[i] = targets[(size_t)b * NOBJ_ * 6 + i];
    __syncthreads();
    size_t ip = (size_t)b * P_ + p;
    float ov = btovl[ip];
    int   ti = btidx[ip];
    float w  = tg[ti*6+5];
    bool pos = ov >= THRESH_;
    int  tgt = pos ? (int)tg[ti*6+4] : 0;

    float tx1 = tg[ti*6+0], ty1 = tg[ti*6+1], tx2 = tg[ti*6+2], ty2 = tg[ti*6+3];
    float cx = priors[p*4], cy = priors[p*4+1], pw = priors[p*4+2], ph = priors[p*4+3];
    float gx = ((tx1 + tx2) * 0.5f - cx) / (0.1f * pw);
    float gy = ((ty1 + ty2) * 0.5f - cy) / (0.1f * ph);
    float gw = logf((tx2 - tx1) / pw) * 5.0f;
    float gh = logf((ty2 - ty1) / ph) * 5.0f;

    const float* lr = loc + ip * 4;
    float sl1 = 0.f;
    {
        float g[4] = {gx, gy, gw, gh};
        #pragma unroll
        for (int k = 0; k < 4; ++k) {
            float d = lr[k] - g[k];
            float ad = fabsf(d);
            sl1 += (ad < 1.0f) ? 0.5f * d * d : ad - 0.5f;
        }
    }

    float o0 = obj[ip*2], o1 = obj[ip*2+1];
    float mo = fmaxf(o0, o1);
    float lae = mo + logf(expf(o0 - mo) + expf(o1 - mo));

    const float4* cr = (const float4*)(conf + ip * C_);
    float m = -INFINITY, s = 0.f;
    #pragma unroll 4
    for (int k = 0; k < C_ / 4; ++k) {
        float4 v = cr[k];
        float m4 = fmaxf(fmaxf(v.x, v.y), fmaxf(v.z, v.w));
        float nm = fmaxf(m, m4);
        s = s * expf(m - nm) + expf(v.x - nm) + expf(v.y - nm) + expf(v.z - nm) + expf(v.w - nm);
        m = nm;
    }
    float lse = m + logf(s);

    float ce_o = lae - (pos ? o1 : o0);
    float ce_c;
    if (tgt == 0) {
        ce_c = lae - o0;
    } else {
        float ctgt = conf[ip * C_ + (tgt - 1)];
        ce_c = lse + lae - o1 - ctgt;
    }

    mine_c[ip] = pos ? 0.f : ce_c;
    mine_o[ip] = pos ? 0.f : ce_o;
    wArr[ip]   = w;
    posArr[ip] = pos ? 1 : 0;

    double pl = pos ? (double)(sl1 * w)  : 0.0;
    double pc = pos ? (double)(ce_c * w) : 0.0;
    double po = pos ? (double)(ce_o * w) : 0.0;
    double pn = pos ? (double)w          : 0.0;

    double r;
    r = block_reduce_d(pl, rd, 256); if (threadIdx.x == 0) atomicAdd(&acc[0], r);
    r = block_reduce_d(pc, rd, 256); if (threadIdx.x == 0) atomicAdd(&acc[1], r);
    r = block_reduce_d(po, rd, 256); if (threadIdx.x == 0) atomicAdd(&acc[2], r);
    r = block_reduce_d(pn, rd, 256); if (threadIdx.x == 0) atomicAdd(&acc[3 + b], r);
}

__global__ void k_numneg(const double* __restrict__ acc, int* __restrict__ num_neg)
{
    int b = threadIdx.x;
    if (b >= B_) return;
    int np = (int)acc[3 + b];
    int nn = 3 * np;
    num_neg[b] = nn < (P_ - 1) ? nn : (P_ - 1);
}

#define SEL_T 1024
#define TIE_CAP 1024

// Parallel crossing-point finder: after hist[] holds a suffix-inclusive
// cumulative sum c[b] = sum_{b'>=b} h[b'], find the highest bin with
// c[bin] >= K. pre = c[bin+1] (count strictly above bin).
__device__ __forceinline__ void suffix_scan_2048(unsigned* c) {
    int tid = threadIdx.x;
    #pragma unroll
    for (int s = 1; s < 2048; s <<= 1) {
        unsigned a0 = (tid + s < 2048) ? c[tid + s] : 0u;
        unsigned a1 = (tid + 1024 + s < 2048) ? c[tid + 1024 + s] : 0u;
        __syncthreads();
        c[tid] += a0;
        c[tid + 1024] += a1;
        __syncthreads();
    }
}

__device__ __forceinline__ void find_bin(unsigned* c, int K, int* s_bin, int* s_pre) {
    int tid = threadIdx.x;
    #pragma unroll
    for (int i = 0; i < 2; ++i) {
        int bb = tid + i * 1024;
        unsigned cb = c[bb];
        unsigned cn = (bb == 2047) ? 0u : c[bb + 1];
        if (cb >= (unsigned)K && cn < (unsigned)K) { *s_bin = bb; *s_pre = (int)cn; }
    }
    __syncthreads();
}

// Exact top-K selection per (batch, branch) via 3-pass radix histogram.
// Fully parallel: suffix-scan threshold finding + LDS tie-list (no O(P)
// serial loops, no tid0 serial bin scan).
__global__ __launch_bounds__(SEL_T) void k_select(
    const float* __restrict__ mine_c, const float* __restrict__ mine_o,
    const float* __restrict__ wArr, const uint8_t* __restrict__ posArr,
    const int* __restrict__ num_neg, double* __restrict__ acc)
{
    int b = blockIdx.x;
    int branch = blockIdx.y; // 0 = conf, 1 = obj
    int tid = threadIdx.x;
    int K = num_neg[b];
    if (K <= 0) return;

    const float* mrow = (branch ? mine_o : mine_c) + (size_t)b * P_;
    const float* wrow = wArr + (size_t)b * P_;
    const uint8_t* prow = posArr + (size_t)b * P_;

    __shared__ unsigned hist[2048];
    __shared__ int s_bin, s_pre;
    __shared__ int tcnt;
    __shared__ int tlist[TIE_CAP];
    __shared__ double rd[SEL_T];

    // ---- pass 1: bits [31:21] ----
    hist[tid] = 0; hist[tid + 1024] = 0;
    __syncthreads();
    for (int p = tid; p < P_; p += SEL_T) wave_hist_add(fkey(mrow[p]) >> 21, hist);
    __syncthreads();
    suffix_scan_2048(hist);
    find_bin(hist, K, &s_bin, &s_pre);
    int bin1 = s_bin, pre1 = s_pre;
    __syncthreads();

    // ---- pass 2: bits [20:10] among elements with top bits == bin1 ----
    hist[tid] = 0; hist[tid + 1024] = 0;
    __syncthreads();
    for (int p = tid; p < P_; p += SEL_T) {
        unsigned k = fkey(mrow[p]);
        if ((int)(k >> 21) == bin1) wave_hist_add((k >> 10) & 0x7FFu, hist);
    }
    __syncthreads();
    suffix_scan_2048(hist);
    find_bin(hist, K - pre1, &s_bin, &s_pre);
    int bin2 = s_bin, pre2 = s_pre;
    __syncthreads();

    // ---- pass 3: bits [9:0] ----
    hist[tid] = 0; hist[tid + 1024] = 0;
    __syncthreads();
    unsigned hi21 = ((unsigned)bin1 << 11) | (unsigned)bin2;
    for (int p = tid; p < P_; p += SEL_T) {
        unsigned k = fkey(mrow[p]);
        if ((k >> 10) == hi21) wave_hist_add(k & 0x3FFu, hist);
    }
    __syncthreads();
    suffix_scan_2048(hist);
    find_bin(hist, K - pre1 - pre2, &s_bin, &s_pre);
    int bin3 = s_bin, pre3 = s_pre;
    __syncthreads();

    unsigned T = (hi21 << 10) | (unsigned)bin3;
    int mslots = K - (pre1 + pre2 + pre3);  // ties selected, smallest index first

    // ---- gather tie indices (typically 1) and sum k > T ----
    if (tid == 0) tcnt = 0;
    __syncthreads();
    double sum = 0.0;
    for (int p = tid; p < P_; p += SEL_T) {
        float v = mrow[p];
        unsigned k = fkey(v);
        if (k > T) {
            if (!prow[p]) sum += (double)v * (double)wrow[p];
        } else if (k == T && !prow[p] && v != 0.0f) {
            int slot = atomicAdd(&tcnt, 1);
            if (slot < TIE_CAP) tlist[slot] = p;
        }
    }
    __syncthreads();
    int n = tcnt < TIE_CAP ? tcnt : TIE_CAP;
    if (tid < n) {
        int myp = tlist[tid];
        bool sel;
        if (n <= mslots) {
            sel = true;
        } else {
            int r = 0;
            for (int j = 0; j < n; ++j) if (tlist[j] < myp) ++r;
            sel = (r < mslots);
        }
        if (sel) sum += (double)mrow[myp] * (double)wrow[myp];
    }
    double r = block_reduce_d(sum, rd, SEL_T);
    if (tid == 0) atomicAdd(&acc[1 + branch], r);
}

__global__ void k_final(const double* __restrict__ acc, float* __restrict__ out)
{
    if (threadIdx.x == 0) {
        double N = 0.0;
        for (int b = 0; b < B_; ++b) N += acc[3 + b];
        out[0] = (float)(acc[0] / N);
        out[1] = (float)(acc[1] / N);
        out[2] = (float)(acc[2] / N);
    }
}

extern "C" void kernel_launch(void* const* d_in, const int* in_sizes, int n_in,
                              void* d_out, int out_size, void* d_ws, size_t ws_size,
                              hipStream_t stream)
{
    const float* loc     = (const float*)d_in[0];
    const float* conf    = (const float*)d_in[1];
    const float* obj     = (const float*)d_in[2];
    const float* priors  = (const float*)d_in[3];
    const float* targets = (const float*)d_in[4];
    float* out = (float*)d_out;

    char* ws = (char*)d_ws;
    double*  acc    = (double*)(ws + OFF_ACC);
    int*     nneg   = (int*)(ws + OFF_NNEG);
    int*     bp     = (int*)(ws + OFF_BP);
    float*   btovl  = (float*)(ws + OFF_BTOVL);
    int*     btidx  = (int*)(ws + OFF_BTIDX);
    float*   mine_c = (float*)(ws + OFF_MINEC);
    float*   mine_o = (float*)(ws + OFF_MINEO);
    float*   wArr   = (float*)(ws + OFF_W);
    uint8_t* posArr = (uint8_t*)(ws + OFF_POS);

    hipMemsetAsync(ws, 0, 512, stream);

    k_match_prior<<<dim3(P_/256, B_), 256, 0, stream>>>(priors, targets, btovl, btidx);
    k_best_prior <<<dim3(NOBJ_, B_), 256, 0, stream>>>(priors, targets, bp);
    k_scatter    <<<1, 64, 0, stream>>>(bp, btovl, btidx);
    k_main       <<<dim3(P_/256, B_), 256, 0, stream>>>(loc, conf, obj, priors, targets,
                                                        btovl, btidx, mine_c, mine_o,
                                                        wArr, posArr, acc);
    k_numneg     <<<1, 64, 0, stream>>>(acc, nneg);
    k_select     <<<dim3(B_, 2), SEL_T, 0, stream>>>(mine_c, mine_o, wArr, posArr, nneg, acc);
    k_final      <<<1, 64, 0, stream>>>(acc, out);
}